// Round 1
// baseline (728.444 us; speedup 1.0000x reference)
//
#include <hip/hip_runtime.h>
#include <hip/hip_bf16.h>

#define TSTEPS 200
#define RS 25800  // T*129

typedef __attribute__((ext_vector_type(8))) short short8;
typedef __attribute__((ext_vector_type(4))) float f32x4;
typedef __attribute__((ext_vector_type(4), aligned(4))) float f32x4u;  // 4B-aligned (t*129 breaks 16B)

__device__ __forceinline__ short f2bf(float f){
  return (short)__builtin_bit_cast(unsigned short, __float2bfloat16(f));
}
__device__ __forceinline__ float bf2f(short s){
  unsigned u = ((unsigned)(unsigned short)s) << 16;
  return __builtin_bit_cast(float, u);
}
__device__ __forceinline__ float sigm(float x){ return 1.0f/(1.0f + __expf(-x)); }
__device__ __forceinline__ float tanh_(float x){ return 1.0f - 2.0f/(1.0f + __expf(2.0f*x)); }

#define MFMA16(a,b,c) __builtin_amdgcn_mfma_f32_16x16x32_bf16((a),(b),(c),0,0,0)

// h LDS tile: [buf][hi/lo][16 rows][stride 136 shorts] -> row*272B stride, bank-offset 4/row,
// gives minimum 8 phases for the ds_read_b128 A-fragment pattern (no swizzle needed).
#define HSTR 136

__global__ __launch_bounds__(256, 1) void gru_fused(
    const float* __restrict__ inp, const float* __restrict__ h0,
    const float* __restrict__ Wr, const float* __restrict__ Ur, const float* __restrict__ br,
    const float* __restrict__ Wz, const float* __restrict__ Uz, const float* __restrict__ bz,
    const float* __restrict__ Wh, const float* __restrict__ Uh, const float* __restrict__ bh,
    float* __restrict__ out)
{
  __shared__ short hlds[2][2][16*HSTR];

  const int tid  = threadIdx.x;
  const int lane = tid & 63;
  const int w    = tid >> 6;       // wave 0..3: owns cols [32w,32w+32)
  const int l15  = lane & 15;
  const int l4   = lane >> 4;      // 0..3
  const int b0   = blockIdx.x * 16;

  // ---- weight B-fragments, bf16, registers (lane: col=l15, k=l4*8+e) ----
  short8 BW[6][2][4];  // [mat: Wr,Ur,Wz,Uz,Wh,Uh][n-tile][k-step]
  {
    const float* Wm[6] = {Wr, Ur, Wz, Uz, Wh, Uh};
    #pragma unroll
    for (int m = 0; m < 6; ++m)
      #pragma unroll
      for (int tl = 0; tl < 2; ++tl)
        #pragma unroll
        for (int kk = 0; kk < 4; ++kk){
          short8 f;
          #pragma unroll
          for (int e = 0; e < 8; ++e)
            f[e] = f2bf(Wm[m][(size_t)(kk*32 + l4*8 + e)*128 + (w*32 + tl*16 + l15)]);
          BW[m][tl][kk] = f;
        }
  }

  // biases per owned column
  float bR[2], bZ[2], bH[2];
  #pragma unroll
  for (int tl = 0; tl < 2; ++tl){
    int c = w*32 + tl*16 + l15;
    bR[tl] = br[c]; bZ[tl] = bz[c]; bH[tl] = bh[c];
  }

  // h0 -> fp32 master regs (C-frag layout: row=l4*4+j, col owned) + LDS buf0 (hi/lo bf16)
  float hprev[2][4];
  #pragma unroll
  for (int tl = 0; tl < 2; ++tl)
    #pragma unroll
    for (int j = 0; j < 4; ++j){
      int row = l4*4 + j;
      int col = w*32 + tl*16 + l15;
      float h = h0[(size_t)(b0+row)*128 + col];
      hprev[tl][j] = h;
      short hi = f2bf(h);
      short lo = f2bf(h - bf2f(hi));
      hlds[0][0][row*HSTR + col] = hi;
      hlds[0][1][row*HSTR + col] = lo;
    }

  // ---- prefetch x(0), a(0) into registers (x loads land in native A-frag layout) ----
  const float* xbase = inp + (size_t)(b0 + l15)*RS + l4*8;
  f32x4 xb[4][2];
  float abuf[4];
  #pragma unroll
  for (int kk = 0; kk < 4; ++kk){
    xb[kk][0] = *(const f32x4u*)(xbase + kk*32);
    xb[kk][1] = *(const f32x4u*)(xbase + kk*32 + 4);
  }
  #pragma unroll
  for (int j = 0; j < 4; ++j)
    abuf[j] = inp[(size_t)(b0 + l4*4 + j)*RS + 128];

  __syncthreads();

  for (int t = 0; t < TSTEPS; ++t){
    // consume prefetched x (convert to bf16 A-frags) and a
    short8 xf[4];
    #pragma unroll
    for (int kk = 0; kk < 4; ++kk){
      short8 f;
      #pragma unroll
      for (int e = 0; e < 4; ++e) f[e]   = f2bf(xb[kk][0][e]);
      #pragma unroll
      for (int e = 0; e < 4; ++e) f[4+e] = f2bf(xb[kk][1][e]);
      xf[kk] = f;
    }
    float acur[4];
    #pragma unroll
    for (int j = 0; j < 4; ++j) acur[j] = abuf[j];

    // issue prefetch for t+1 (clamped; latency hides under this step's body)
    {
      int tn = (t < TSTEPS-1) ? (t+1) : t;
      const float* p = xbase + (size_t)tn*129;
      #pragma unroll
      for (int kk = 0; kk < 4; ++kk){
        xb[kk][0] = *(const f32x4u*)(p + kk*32);
        xb[kk][1] = *(const f32x4u*)(p + kk*32 + 4);
      }
      #pragma unroll
      for (int j = 0; j < 4; ++j)
        abuf[j] = inp[(size_t)(b0 + l4*4 + j)*RS + (size_t)tn*129 + 128];
    }

    // h A-fragments (hi/lo) from LDS buf[t&1]
    const short* hbhi = &hlds[t&1][0][0];
    const short* hblo = &hlds[t&1][1][0];
    short8 hhi[4], hlo4[4];
    {
      int base = l15*HSTR + l4*8;
      #pragma unroll
      for (int kk = 0; kk < 4; ++kk){
        hhi[kk]  = *(const short8*)(hbhi + base + kk*32);
        hlo4[kk] = *(const short8*)(hblo + base + kk*32);
      }
    }

    // MFMA accumulate: R = b_r + xWr + hUr, Z = b_z + xWz + hUz, XH = b_h + xWh, HH = hUh
    f32x4 aR[2], aZ[2], aXH[2], aHH[2];
    #pragma unroll
    for (int tl = 0; tl < 2; ++tl){
      f32x4 r0, z0, x0, h0v;
      r0[0]=r0[1]=r0[2]=r0[3]=bR[tl];
      z0[0]=z0[1]=z0[2]=z0[3]=bZ[tl];
      x0[0]=x0[1]=x0[2]=x0[3]=bH[tl];
      h0v[0]=h0v[1]=h0v[2]=h0v[3]=0.0f;
      aR[tl]=r0; aZ[tl]=z0; aXH[tl]=x0; aHH[tl]=h0v;
    }
    #pragma unroll
    for (int tl = 0; tl < 2; ++tl){
      #pragma unroll
      for (int kk = 0; kk < 4; ++kk){
        aR[tl]  = MFMA16(xf[kk],   BW[0][tl][kk], aR[tl]);
        aZ[tl]  = MFMA16(xf[kk],   BW[2][tl][kk], aZ[tl]);
        aXH[tl] = MFMA16(xf[kk],   BW[4][tl][kk], aXH[tl]);
        aR[tl]  = MFMA16(hhi[kk],  BW[1][tl][kk], aR[tl]);
        aZ[tl]  = MFMA16(hhi[kk],  BW[3][tl][kk], aZ[tl]);
        aHH[tl] = MFMA16(hhi[kk],  BW[5][tl][kk], aHH[tl]);
        aR[tl]  = MFMA16(hlo4[kk], BW[1][tl][kk], aR[tl]);
        aZ[tl]  = MFMA16(hlo4[kk], BW[3][tl][kk], aZ[tl]);
        aHH[tl] = MFMA16(hlo4[kk], BW[5][tl][kk], aHH[tl]);
      }
    }

    // elementwise gates + h update (fp32 master), write h(t+1) hi/lo to LDS, store out
    short* nxhi = &hlds[(t+1)&1][0][0];
    short* nxlo = &hlds[(t+1)&1][1][0];
    #pragma unroll
    for (int tl = 0; tl < 2; ++tl)
      #pragma unroll
      for (int j = 0; j < 4; ++j){
        int row = l4*4 + j;
        int col = w*32 + tl*16 + l15;
        float r  = sigm(aR[tl][j]);
        float z  = sigm(aZ[tl][j]);
        float ht = tanh_(aXH[tl][j] + r*aHH[tl][j]);
        float uh = acur[j]*z;
        float hp = hprev[tl][j];
        float h  = hp + uh*(ht - hp);
        hprev[tl][j] = h;
        out[((size_t)(b0+row)*TSTEPS + t)*128 + col] = h;
        short hi = f2bf(h);
        short lo = f2bf(h - bf2f(hi));
        nxhi[row*HSTR + col] = hi;
        nxlo[row*HSTR + col] = lo;
      }
    __syncthreads();
  }
}

extern "C" void kernel_launch(void* const* d_in, const int* in_sizes, int n_in,
                              void* d_out, int out_size, void* d_ws, size_t ws_size,
                              hipStream_t stream)
{
  (void)in_sizes; (void)n_in; (void)d_ws; (void)ws_size; (void)out_size;
  gru_fused<<<128, 256, 0, stream>>>(
      (const float*)d_in[0], (const float*)d_in[1],
      (const float*)d_in[2], (const float*)d_in[3], (const float*)d_in[4],
      (const float*)d_in[5], (const float*)d_in[6], (const float*)d_in[7],
      (const float*)d_in[8], (const float*)d_in[9], (const float*)d_in[10],
      (float*)d_out);
}

// Round 4
// 648.634 us; speedup vs baseline: 1.1230x; 1.1230x over previous
//
#include <hip/hip_runtime.h>
#include <hip/hip_bf16.h>

#define TSTEPS 200
#define RS 25800  // T*129

typedef __attribute__((ext_vector_type(8))) short short8;
typedef __attribute__((ext_vector_type(4))) float f32x4;
typedef __attribute__((ext_vector_type(4), aligned(4))) float f32x4u;  // 4B-aligned (t*129 breaks 16B)

__device__ __forceinline__ short f2bf(float f){
  return (short)__builtin_bit_cast(unsigned short, __float2bfloat16(f));
}
__device__ __forceinline__ float bf2f(short s){
  unsigned u = ((unsigned)(unsigned short)s) << 16;
  return __builtin_bit_cast(float, u);
}
// approximate rcp (v_rcp_f32, ~1e-6 rel err): replaces full-precision fp32 divide
__device__ __forceinline__ float rcpf_(float x){ return __builtin_amdgcn_rcpf(x); }
__device__ __forceinline__ float sigm(float x){ return rcpf_(1.0f + __expf(-x)); }
__device__ __forceinline__ float tanh_(float x){ return 1.0f - 2.0f*rcpf_(1.0f + __expf(2.0f*x)); }

#define MFMA16(a,b,c) __builtin_amdgcn_mfma_f32_16x16x32_bf16((a),(b),(c),0,0,0)

// h LDS tile: [buf][hi/lo][16 rows][stride 136 shorts]
#define HSTR 136

// 8 waves (512 threads): wave w owns output cols [16w, 16w+16).
// 2 waves/SIMD for latency hiding; BW down to 24 short8 = 96 VGPR/wave.
__global__ __launch_bounds__(512, 2) void gru_fused(
    const float* __restrict__ inp, const float* __restrict__ h0,
    const float* __restrict__ Wr, const float* __restrict__ Ur, const float* __restrict__ br,
    const float* __restrict__ Wz, const float* __restrict__ Uz, const float* __restrict__ bz,
    const float* __restrict__ Wh, const float* __restrict__ Uh, const float* __restrict__ bh,
    float* __restrict__ out)
{
  __shared__ short hlds[2][2][16*HSTR];

  const int tid  = threadIdx.x;
  const int lane = tid & 63;
  const int w    = tid >> 6;       // wave 0..7
  const int l15  = lane & 15;
  const int l4   = lane >> 4;      // 0..3
  const int b0   = blockIdx.x * 16;
  const int col  = w*16 + l15;     // owned output column

  // ---- weight B-fragments, bf16, registers (lane: col=l15 within 16-col slice, k=l4*8+e) ----
  short8 BW[6][4];  // [mat: Wr,Ur,Wz,Uz,Wh,Uh][k-step]
  {
    const float* Wm[6] = {Wr, Ur, Wz, Uz, Wh, Uh};
    #pragma unroll
    for (int m = 0; m < 6; ++m)
      #pragma unroll
      for (int kk = 0; kk < 4; ++kk){
        short8 f;
        #pragma unroll
        for (int e = 0; e < 8; ++e)
          f[e] = f2bf(Wm[m][(size_t)(kk*32 + l4*8 + e)*128 + col]);
        BW[m][kk] = f;
      }
  }

  const float bR = br[col], bZ = bz[col], bH = bh[col];

  // h0 -> fp32 master regs (C-frag layout: row=l4*4+j, col owned) + LDS buf0 (hi/lo bf16)
  float hprev[4];
  #pragma unroll
  for (int j = 0; j < 4; ++j){
    int row = l4*4 + j;
    float h = h0[(size_t)(b0+row)*128 + col];
    hprev[j] = h;
    short hi = f2bf(h);
    short lo = f2bf(h - bf2f(hi));
    hlds[0][0][row*HSTR + col] = hi;
    hlds[0][1][row*HSTR + col] = lo;
  }

  // ---- prefetch x(0), a(0) into registers (x loads land in native A-frag layout) ----
  const float* xbase = inp + (size_t)(b0 + l15)*RS + l4*8;
  f32x4 xb[4][2];
  float abuf[4];
  #pragma unroll
  for (int kk = 0; kk < 4; ++kk){
    xb[kk][0] = *(const f32x4u*)(xbase + kk*32);
    xb[kk][1] = *(const f32x4u*)(xbase + kk*32 + 4);
  }
  #pragma unroll
  for (int j = 0; j < 4; ++j)
    abuf[j] = inp[(size_t)(b0 + l4*4 + j)*RS + 128];

  __syncthreads();

  for (int t = 0; t < TSTEPS; ++t){
    // issue h A-fragment ds_reads first (latency hides under x-convert + x-MFMAs)
    const short* hbhi = &hlds[t&1][0][0];
    const short* hblo = &hlds[t&1][1][0];
    short8 hhi[4], hlo4[4];
    {
      int base = l15*HSTR + l4*8;
      #pragma unroll
      for (int kk = 0; kk < 4; ++kk){
        hhi[kk]  = *(const short8*)(hbhi + base + kk*32);
        hlo4[kk] = *(const short8*)(hblo + base + kk*32);
      }
    }

    // consume prefetched x (convert to bf16 A-frags) and a
    short8 xf[4];
    #pragma unroll
    for (int kk = 0; kk < 4; ++kk){
      short8 f;
      #pragma unroll
      for (int e = 0; e < 4; ++e) f[e]   = f2bf(xb[kk][0][e]);
      #pragma unroll
      for (int e = 0; e < 4; ++e) f[4+e] = f2bf(xb[kk][1][e]);
      xf[kk] = f;
    }
    float acur[4];
    #pragma unroll
    for (int j = 0; j < 4; ++j) acur[j] = abuf[j];

    // issue prefetch for t+1 (clamped; latency hides under this step's body)
    {
      int tn = (t < TSTEPS-1) ? (t+1) : t;
      const float* p = xbase + (size_t)tn*129;
      #pragma unroll
      for (int kk = 0; kk < 4; ++kk){
        xb[kk][0] = *(const f32x4u*)(p + kk*32);
        xb[kk][1] = *(const f32x4u*)(p + kk*32 + 4);
      }
      #pragma unroll
      for (int j = 0; j < 4; ++j)
        abuf[j] = inp[(size_t)(b0 + l4*4 + j)*RS + (size_t)tn*129 + 128];
    }

    // MFMA accumulate: R = b_r + xWr + hUr, Z = b_z + xWz + hUz, XH = b_h + xWh, HH = hUh
    f32x4 aR, aZ, aXH, aHH;
    aR[0]=aR[1]=aR[2]=aR[3]=bR;
    aZ[0]=aZ[1]=aZ[2]=aZ[3]=bZ;
    aXH[0]=aXH[1]=aXH[2]=aXH[3]=bH;
    aHH[0]=aHH[1]=aHH[2]=aHH[3]=0.0f;

    // x-MFMAs first: no dependence on the h ds_reads still in flight
    #pragma unroll
    for (int kk = 0; kk < 4; ++kk){
      aR  = MFMA16(xf[kk], BW[0][kk], aR);
      aZ  = MFMA16(xf[kk], BW[2][kk], aZ);
      aXH = MFMA16(xf[kk], BW[4][kk], aXH);
    }
    // h-MFMAs (hi + lo split for accuracy)
    #pragma unroll
    for (int kk = 0; kk < 4; ++kk){
      aR  = MFMA16(hhi[kk],  BW[1][kk], aR);
      aZ  = MFMA16(hhi[kk],  BW[3][kk], aZ);
      aHH = MFMA16(hhi[kk],  BW[5][kk], aHH);
      aR  = MFMA16(hlo4[kk], BW[1][kk], aR);
      aZ  = MFMA16(hlo4[kk], BW[3][kk], aZ);
      aHH = MFMA16(hlo4[kk], BW[5][kk], aHH);
    }

    // elementwise gates + h update (fp32 master), write h(t+1) hi/lo to LDS, store out
    short* nxhi = &hlds[(t+1)&1][0][0];
    short* nxlo = &hlds[(t+1)&1][1][0];
    #pragma unroll
    for (int j = 0; j < 4; ++j){
      int row = l4*4 + j;
      float r  = sigm(aR[j]);
      float z  = sigm(aZ[j]);
      float ht = tanh_(aXH[j] + r*aHH[j]);
      float uh = acur[j]*z;
      float hp = hprev[j];
      float h  = hp + uh*(ht - hp);
      hprev[j] = h;
      out[((size_t)(b0+row)*TSTEPS + t)*128 + col] = h;
      short hi = f2bf(h);
      short lo = f2bf(h - bf2f(hi));
      nxhi[row*HSTR + col] = hi;
      nxlo[row*HSTR + col] = lo;
    }
    __syncthreads();
  }
}

extern "C" void kernel_launch(void* const* d_in, const int* in_sizes, int n_in,
                              void* d_out, int out_size, void* d_ws, size_t ws_size,
                              hipStream_t stream)
{
  (void)in_sizes; (void)n_in; (void)d_ws; (void)ws_size; (void)out_size;
  gru_fused<<<128, 512, 0, stream>>>(
      (const float*)d_in[0], (const float*)d_in[1],
      (const float*)d_in[2], (const float*)d_in[3], (const float*)d_in[4],
      (const float*)d_in[5], (const float*)d_in[6], (const float*)d_in[7],
      (const float*)d_in[8], (const float*)d_in[9], (const float*)d_in[10],
      (float*)d_out);
}